// Round 4
// baseline (559.450 us; speedup 1.0000x reference)
//
#include <hip/hip_runtime.h>

#define D_MODEL 2048
#define N_HEADS 32
#define N_KV    8
#define D_HEAD  64
#define BATCH   2
#define TLEN    4096
#define WINDOW  1024
#define SINK    4
#define SEQ_S   (WINDOW + SINK)      /* 1028 */
#define S_PADN  1088                 /* 17 steps x 64 */
#define MROWS   (BATCH * TLEN)       /* 8192 */
#define KV_DIM  512
#define KV_STR  1024                 /* merged kv_buf row stride */
#define LOG2E   1.44269504088896340736f
#define PSP     72                   /* P LDS row pad (elements) */

typedef __bf16 bf16_t;
typedef __attribute__((ext_vector_type(8))) __bf16 bf16x8;
typedef __attribute__((ext_vector_type(4))) __bf16 bf16x4;
typedef __attribute__((ext_vector_type(4))) float   f32x4;

__device__ __forceinline__ void load_lds16(const void* g, void* l) {
  __builtin_amdgcn_global_load_lds(
      (__attribute__((address_space(1))) void*)g,
      (__attribute__((address_space(3))) void*)l, 16, 0, 0);
}

// ---------------------------------------------------------------------------
// all 5 fp32->bf16 converts in one launch; dst regions contiguous in ws
// ---------------------------------------------------------------------------
#define NX  (MROWS * D_MODEL)       /* 16777216 */
#define NWQ (D_MODEL * D_MODEL)     /*  4194304 */
#define NWK (KV_DIM * D_MODEL)      /*  1048576 */
#define NALL (NX + 2 * NWQ + 2 * NWK)

__global__ __launch_bounds__(256) void cvt_all(const float* __restrict__ x,
                                               const float* __restrict__ wq,
                                               const float* __restrict__ wk,
                                               const float* __restrict__ wv,
                                               const float* __restrict__ wp,
                                               bf16_t* __restrict__ dst)
{
  long i = ((long)blockIdx.x * 256 + threadIdx.x) * 4;
  const float* src;
  long off;
  if (i < NX)                          { src = x;  off = i; }
  else if (i < NX + NWQ)               { src = wq; off = i - NX; }
  else if (i < NX + NWQ + NWK)         { src = wk; off = i - NX - NWQ; }
  else if (i < NX + NWQ + 2L * NWK)    { src = wv; off = i - NX - NWQ - NWK; }
  else                                 { src = wp; off = i - NX - NWQ - 2L * NWK; }
  const float4 v = *(const float4*)(src + off);
  bf16x4 o;
  o[0] = (bf16_t)v.x; o[1] = (bf16_t)v.y; o[2] = (bf16_t)v.z; o[3] = (bf16_t)v.w;
  *(bf16x4*)(dst + i) = o;
}

// ---------------------------------------------------------------------------
// GEMM: C[M,N] = A[M,K] * W[N,K]^T  (bf16 in, fp32 accum, OutT out)
// ---------------------------------------------------------------------------
template <typename OutT>
__global__ __launch_bounds__(256) void gemm_bt(const bf16_t* __restrict__ A,
                                               const bf16_t* __restrict__ W,
                                               OutT* __restrict__ C,
                                               int M, int N, int K)
{
  __shared__ __align__(16) bf16_t As[128 * 32];
  __shared__ __align__(16) bf16_t Bs[128 * 32];
  const int tid  = threadIdx.x;
  const int lane = tid & 63;
  const int wave = tid >> 6;
  const int quad = lane >> 4;
  const int col  = lane & 15;
  const int wm   = (wave >> 1) * 64;
  const int wn   = (wave & 1) * 64;
  const int bm   = blockIdx.x * 128;
  const int bn   = blockIdx.y * 128;

  const int e0 = tid, e1 = 256 + tid;
  const int r0 = e0 >> 2, c0 = ((e0 & 3) ^ (r0 & 3)) * 8;
  const int r1 = e1 >> 2, c1 = ((e1 & 3) ^ (r1 & 3)) * 8;
  const bf16_t* gA0 = A + (size_t)(bm + r0) * K + c0;
  const bf16_t* gA1 = A + (size_t)(bm + r1) * K + c1;
  const bf16_t* gB0 = W + (size_t)(bn + r0) * K + c0;
  const bf16_t* gB1 = W + (size_t)(bn + r1) * K + c1;
  char* lA0 = (char*)As + wave * 1024;
  char* lA1 = (char*)As + 4096 + wave * 1024;
  char* lB0 = (char*)Bs + wave * 1024;
  char* lB1 = (char*)Bs + 4096 + wave * 1024;

  f32x4 acc[4][4] = {};

  for (int k0 = 0; k0 < K; k0 += 32) {
    __syncthreads();
    load_lds16(gA0 + k0, lA0);
    load_lds16(gA1 + k0, lA1);
    load_lds16(gB0 + k0, lB0);
    load_lds16(gB1 + k0, lB1);
    __syncthreads();
    bf16x8 af[4], bfr[4];
    for (int i = 0; i < 4; ++i) {
      int row = wm + i * 16 + col;
      af[i] = *(const bf16x8*)((const char*)As + row * 64 + ((quad ^ (row & 3)) * 16));
    }
    for (int j = 0; j < 4; ++j) {
      int row = wn + j * 16 + col;
      bfr[j] = *(const bf16x8*)((const char*)Bs + row * 64 + ((quad ^ (row & 3)) * 16));
    }
    for (int i = 0; i < 4; ++i)
      for (int j = 0; j < 4; ++j)
        acc[i][j] = __builtin_amdgcn_mfma_f32_16x16x32_bf16(af[i], bfr[j], acc[i][j], 0, 0, 0);
  }

  for (int i = 0; i < 4; ++i)
    for (int j = 0; j < 4; ++j)
      for (int r = 0; r < 4; ++r) {
        size_t row = (size_t)(bm + wm + i * 16 + quad * 4 + r);
        size_t cc  = (size_t)(bn + wn + j * 16 + col);
        C[row * N + cc] = (OutT)acc[i][j][r];
      }
}

// ---------------------------------------------------------------------------
// RoPE in place on K half of kv [MROWS,1024] (cols 0..511); Q rope is fused
// into the attention kernel.
// ---------------------------------------------------------------------------
__global__ __launch_bounds__(256) void rope_k(bf16_t* __restrict__ kv)
{
  size_t idx = (size_t)blockIdx.x * 256 + threadIdx.x;   // < MROWS*8*32
  int i = (int)(idx & 31);
  size_t hm = idx >> 5;
  int h = (int)(hm & (N_KV - 1));
  size_t m = hm >> 3;
  int t = (int)(m & (TLEN - 1));
  float inv = __builtin_exp2f(-(float)i * (13.287712379549449f / 32.0f));
  float ang = (float)t * inv;
  float sn, cs;
  sincosf(ang, &sn, &cs);
  size_t off = m * (size_t)KV_STR + (size_t)h * D_HEAD + i;
  float x1 = (float)kv[off];
  float x2 = (float)kv[off + 32];
  kv[off]      = (bf16_t)(x1 * cs - x2 * sn);
  kv[off + 32] = (bf16_t)(x2 * cs + x1 * sn);
}

// ---------------------------------------------------------------------------
// V slice+transpose: kv_buf v-part -> Vt [B*KV][64][S_PADN]
// ---------------------------------------------------------------------------
__global__ __launch_bounds__(256) void transpose_v(const bf16_t* __restrict__ KV,
                                                   bf16_t* __restrict__ Vt)
{
  __shared__ __align__(16) bf16_t tile[32][72];
  const int tid = threadIdx.x;
  const int s0  = blockIdx.x * 32;
  const int bk  = blockIdx.y;
  const int b   = bk >> 3, kvh = bk & 7;
  {
    int srow = tid >> 3;
    int dcol = (tid & 7) * 8;
    int sg = s0 + srow;
    int orig = (sg < SINK) ? sg : sg + (TLEN - WINDOW - SINK);
    if (orig > TLEN - 1) orig = TLEN - 1;   // pad rows: masked later
    const bf16_t* src = KV + (size_t)(b * TLEN + orig) * KV_STR + KV_DIM + kvh * D_HEAD + dcol;
    *(bf16x8*)&tile[srow][dcol] = *(const bf16x8*)src;
  }
  __syncthreads();
  {
    int d  = tid >> 2;
    int sc = (tid & 3) * 8;
    bf16x8 v;
    for (int j = 0; j < 8; ++j) v[j] = tile[sc + j][d];
    *(bf16x8*)(Vt + (size_t)(bk * 64 + d) * S_PADN + s0 + sc) = v;
  }
}

// ---------------------------------------------------------------------------
// Flash attention v4:
//  - 1 barrier/step (P round-trip is per-wave LDS: no cross-wave sync needed);
//    stage(st+1) issued immediately after the barrier (full-step overlap).
//  - V fragments loaded straight from L2-resident Vt into registers.
//  - row-sum l computed by MFMA against a ones-fragment (matrix pipe, not VALU).
//  - Q RoPE + 0.125*log2(e) scale fused into the Q fragment load.
//  - LDS 34.4KB -> 4 blocks/CU.
// ---------------------------------------------------------------------------
__global__ __launch_bounds__(256, 4) void attn_kernel(const bf16_t* __restrict__ Q,
                                                      const bf16_t* __restrict__ KV,
                                                      const bf16_t* __restrict__ Vt,
                                                      bf16_t* __restrict__ ctx)
{
  __shared__ __align__(16) bf16_t Ks[2][64 * 64];
  __shared__ __align__(16) bf16_t Ps[4][32 * PSP];
  const int tid = threadIdx.x, lane = tid & 63, wave = tid >> 6;
  const int quad = lane >> 4, col = lane & 15;
  const int bh = blockIdx.y, b = bh >> 5, h = bh & 31, kvh = h >> 2;
  const int bkv = b * 8 + kvh;
  const int t0b = blockIdx.x * 128;
  const int tw0 = t0b + wave * 32;

  // ---- Q B-frags with fused RoPE; pair (d, d+32) = (c=0, c=1) same jj ----
  bf16x8 qf[2][2];
  {
    float invf[8];
#pragma unroll
    for (int jj = 0; jj < 8; ++jj)
      invf[jj] = __builtin_exp2f(-(float)(quad * 8 + jj) * (13.287712379549449f / 32.0f));
#pragma unroll
    for (int g = 0; g < 2; ++g) {
      const float tpos = (float)(tw0 + g * 16 + col);
      const bf16_t* qrow = Q + (size_t)(b * TLEN + tw0 + g * 16 + col) * D_MODEL + h * D_HEAD;
      bf16x8 v0 = *(const bf16x8*)(qrow + quad * 8);
      bf16x8 v1 = *(const bf16x8*)(qrow + 32 + quad * 8);
#pragma unroll
      for (int jj = 0; jj < 8; ++jj) {
        float sn, cs;
        sincosf(tpos * invf[jj], &sn, &cs);
        float x1 = (float)v0[jj], x2 = (float)v1[jj];
        qf[g][0][jj] = (bf16_t)((x1 * cs - x2 * sn) * (0.125f * LOG2E));
        qf[g][1][jj] = (bf16_t)((x2 * cs + x1 * sn) * (0.125f * LOG2E));
      }
    }
  }

  bf16x8 ones;
#pragma unroll
  for (int j = 0; j < 8; ++j) ones[j] = (bf16_t)1.0f;

  f32x4 oAcc[2][4] = {};
  f32x4 oL[2] = {};

  const int s_end  = (t0b + 128 < SEQ_S) ? t0b + 128 : SEQ_S;
  const int nsteps = (s_end + 63) >> 6;

  auto stage = [&](int st, int buf) {
    const int sb = st * 64;
#pragma unroll
    for (int kk = 0; kk < 2; ++kk) {
      int e = kk * 256 + tid;
      int srow = e >> 3;
      int cb = (e & 7) ^ (srow & 7);
      int sg = sb + srow;
      int orig = (sg < SINK) ? sg : sg + (TLEN - WINDOW - SINK);
      if (orig > TLEN - 1) orig = TLEN - 1;
      const bf16_t* gk = KV + (size_t)(b * TLEN + orig) * KV_STR + kvh * D_HEAD + cb * 8;
      load_lds16(gk, (char*)&Ks[buf][0] + kk * 4096 + wave * 1024);
    }
  };

  const bf16_t* vbase = Vt + (size_t)(bkv * 64 + col) * S_PADN;  // +nj*16 rows

  stage(0, 0);
  for (int st = 0; st < nsteps; ++st) {
    const int cur = st & 1;
    const int s0 = st * 64;
    const bool dead = (s0 > tw0 + 31);
    const bool full = (s0 + 63 <= tw0) && (s0 + 63 < SEQ_S);
    __syncthreads();                       // Ks[cur] landed; st-1 reads done
    if (st + 1 < nsteps) stage(st + 1, cur ^ 1);   // overlap entire step

    if (dead) continue;

    // V frags c=0 early (hidden under QK+exp2)
    bf16x8 vf0[4];
#pragma unroll
    for (int nj = 0; nj < 4; ++nj)
      vf0[nj] = *(const bf16x8*)(vbase + (size_t)(nj * 16) * S_PADN + s0 + quad * 8);

    // ---- S^T = K·Q^T, per-mt to keep sacc live range small ----
#pragma unroll
    for (int mt = 0; mt < 4; ++mt) {
      const int rr = mt * 16 + col;
      f32x4 sa0 = {0.f, 0.f, 0.f, 0.f}, sa1 = {0.f, 0.f, 0.f, 0.f};
#pragma unroll
      for (int c = 0; c < 2; ++c) {
        const bf16x8 kf = *(const bf16x8*)((const char*)&Ks[cur][0] + rr * 128 +
                                           ((((c << 2) | quad) ^ (col & 7)) * 16));
        sa0 = __builtin_amdgcn_mfma_f32_16x16x32_bf16(kf, qf[0][c], sa0, 0, 0, 0);
        sa1 = __builtin_amdgcn_mfma_f32_16x16x32_bf16(kf, qf[1][c], sa1, 0, 0, 0);
      }
#pragma unroll
      for (int g = 0; g < 2; ++g) {
        const f32x4 sv = g ? sa1 : sa0;
        const int t = tw0 + g * 16 + col;
        bf16x4 pk;
#pragma unroll
        for (int r = 0; r < 4; ++r) {
          float p = __builtin_exp2f(sv[r]);
          if (!full) {
            int s = s0 + mt * 16 + quad * 4 + r;
            p = (s <= t && s < SEQ_S) ? p : 0.0f;
          }
          pk[r] = (bf16_t)p;
        }
        *(bf16x4*)(&Ps[wave][(g * 16 + col) * PSP + mt * 16 + quad * 4]) = pk;
      }
    }

    // V frags c=1 (hidden under P drain + PV c=0)
    bf16x8 vf1[4];
#pragma unroll
    for (int nj = 0; nj < 4; ++nj)
      vf1[nj] = *(const bf16x8*)(vbase + (size_t)(nj * 16) * S_PADN + s0 + 32 + quad * 8);

    // same-wave LDS write->read: in-order, but drain lgkm for safety (free)
    __builtin_amdgcn_s_waitcnt(0xC07F);

#pragma unroll
    for (int c = 0; c < 2; ++c) {
      bf16x8 pf0 = *(const bf16x8*)(&Ps[wave][(col) * PSP + c * 32 + quad * 8]);
      bf16x8 pf1 = *(const bf16x8*)(&Ps[wave][(16 + col) * PSP + c * 32 + quad * 8]);
      oL[0] = __builtin_amdgcn_mfma_f32_16x16x32_bf16(pf0, ones, oL[0], 0, 0, 0);
      oL[1] = __builtin_amdgcn_mfma_f32_16x16x32_bf16(pf1, ones, oL[1], 0, 0, 0);
#pragma unroll
      for (int nj = 0; nj < 4; ++nj) {
        const bf16x8 vf = c ? vf1[nj] : vf0[nj];
        oAcc[0][nj] = __builtin_amdgcn_mfma_f32_16x16x32_bf16(pf0, vf, oAcc[0][nj], 0, 0, 0);
        oAcc[1][nj] = __builtin_amdgcn_mfma_f32_16x16x32_bf16(pf1, vf, oAcc[1][nj], 0, 0, 0);
      }
    }
  }

#pragma unroll
  for (int g = 0; g < 2; ++g) {
    float rli[4];
#pragma unroll
    for (int r = 0; r < 4; ++r)
      rli[r] = __builtin_amdgcn_rcpf(oL[g][r]);
#pragma unroll
    for (int nj = 0; nj < 4; ++nj)
#pragma unroll
      for (int r = 0; r < 4; ++r) {
        size_t row = (size_t)(b * TLEN + tw0 + g * 16 + quad * 4 + r);
        ctx[row * D_MODEL + h * D_HEAD + nj * 16 + col] = (bf16_t)(oAcc[g][nj][r] * rli[r]);
      }
  }
}

// ---------------------------------------------------------------------------
extern "C" void kernel_launch(void* const* d_in, const int* in_sizes, int n_in,
                              void* d_out, int out_size, void* d_ws, size_t ws_size,
                              hipStream_t stream)
{
  const float* x  = (const float*)d_in[0];
  const float* wq = (const float*)d_in[1];
  const float* wk = (const float*)d_in[2];
  const float* wv = (const float*)d_in[3];
  const float* wp = (const float*)d_in[4];

  bf16_t* xb    = (bf16_t*)d_ws;
  bf16_t* wqb   = xb  + (size_t)NX;
  bf16_t* wkb   = wqb + (size_t)NWQ;     // wk rows 0..511
  bf16_t* wvb   = wkb + (size_t)NWK;     // wv rows 512..1023 (contiguous)
  bf16_t* wpb   = wvb + (size_t)NWK;
  bf16_t* q_buf = wpb + (size_t)NWQ;
  bf16_t* kv_buf = q_buf + (size_t)NX;                 // [8192,1024] k|v
  bf16_t* vt_buf = kv_buf + (size_t)MROWS * KV_STR;    // [16,64,S_PADN]
  bf16_t* c_buf  = xb;                                 // reuse x
  float*  out    = (float*)d_out;

  cvt_all<<<NALL / 1024, 256, 0, stream>>>(x, wq, wk, wv, wp, xb);

  gemm_bt<bf16_t><<<dim3(MROWS / 128, D_MODEL / 128), 256, 0, stream>>>(xb, wqb, q_buf, MROWS, D_MODEL, D_MODEL);
  gemm_bt<bf16_t><<<dim3(MROWS / 128, KV_STR / 128), 256, 0, stream>>>(xb, wkb, kv_buf, MROWS, KV_STR, D_MODEL);

  rope_k<<<(MROWS * N_KV * 32) / 256, 256, 0, stream>>>(kv_buf);
  transpose_v<<<dim3(S_PADN / 32, BATCH * N_KV), 256, 0, stream>>>(kv_buf, vt_buf);
  attn_kernel<<<dim3(TLEN / 128, BATCH * N_HEADS), 256, 0, stream>>>(q_buf, kv_buf, vt_buf, c_buf);
  gemm_bt<float><<<dim3(MROWS / 128, D_MODEL / 128), 256, 0, stream>>>(c_buf, wpb, out, MROWS, D_MODEL, D_MODEL);
}

// Round 5
// 538.769 us; speedup vs baseline: 1.0384x; 1.0384x over previous
//
#include <hip/hip_runtime.h>

#define D_MODEL 2048
#define N_HEADS 32
#define N_KV    8
#define D_HEAD  64
#define BATCH   2
#define TLEN    4096
#define WINDOW  1024
#define SINK    4
#define SEQ_S   (WINDOW + SINK)      /* 1028 */
#define S_PADN  1088                 /* 17 steps x 64 */
#define MROWS   (BATCH * TLEN)       /* 8192 */
#define KV_DIM  512
#define KV_STR  1024                 /* merged kv_buf row stride */
#define LOG2E   1.44269504088896340736f
#define PSP     72                   /* P LDS row pad (elements) */

typedef __bf16 bf16_t;
typedef __attribute__((ext_vector_type(8))) __bf16 bf16x8;
typedef __attribute__((ext_vector_type(4))) __bf16 bf16x4;
typedef __attribute__((ext_vector_type(4))) float   f32x4;

__device__ __forceinline__ void load_lds16(const void* g, void* l) {
  __builtin_amdgcn_global_load_lds(
      (__attribute__((address_space(1))) void*)g,
      (__attribute__((address_space(3))) void*)l, 16, 0, 0);
}

// ---------------------------------------------------------------------------
// all 5 fp32->bf16 converts in one launch; dst regions contiguous in ws
// ---------------------------------------------------------------------------
#define NX  (MROWS * D_MODEL)       /* 16777216 */
#define NWQ (D_MODEL * D_MODEL)     /*  4194304 */
#define NWK (KV_DIM * D_MODEL)      /*  1048576 */
#define NALL (NX + 2 * NWQ + 2 * NWK)

__global__ __launch_bounds__(256) void cvt_all(const float* __restrict__ x,
                                               const float* __restrict__ wq,
                                               const float* __restrict__ wk,
                                               const float* __restrict__ wv,
                                               const float* __restrict__ wp,
                                               bf16_t* __restrict__ dst)
{
  long i = ((long)blockIdx.x * 256 + threadIdx.x) * 4;
  const float* src;
  long off;
  if (i < NX)                          { src = x;  off = i; }
  else if (i < NX + NWQ)               { src = wq; off = i - NX; }
  else if (i < NX + NWQ + NWK)         { src = wk; off = i - NX - NWQ; }
  else if (i < NX + NWQ + 2L * NWK)    { src = wv; off = i - NX - NWQ - NWK; }
  else                                 { src = wp; off = i - NX - NWQ - 2L * NWK; }
  const float4 v = *(const float4*)(src + off);
  bf16x4 o;
  o[0] = (bf16_t)v.x; o[1] = (bf16_t)v.y; o[2] = (bf16_t)v.z; o[3] = (bf16_t)v.w;
  *(bf16x4*)(dst + i) = o;
}

// ---------------------------------------------------------------------------
// GEMM: C[M,N] = A[M,K] * W[N,K]^T  (bf16 in, fp32 accum, OutT out)
// ---------------------------------------------------------------------------
template <typename OutT>
__global__ __launch_bounds__(256) void gemm_bt(const bf16_t* __restrict__ A,
                                               const bf16_t* __restrict__ W,
                                               OutT* __restrict__ C,
                                               int M, int N, int K)
{
  __shared__ __align__(16) bf16_t As[128 * 32];
  __shared__ __align__(16) bf16_t Bs[128 * 32];
  const int tid  = threadIdx.x;
  const int lane = tid & 63;
  const int wave = tid >> 6;
  const int quad = lane >> 4;
  const int col  = lane & 15;
  const int wm   = (wave >> 1) * 64;
  const int wn   = (wave & 1) * 64;
  const int bm   = blockIdx.x * 128;
  const int bn   = blockIdx.y * 128;

  const int e0 = tid, e1 = 256 + tid;
  const int r0 = e0 >> 2, c0 = ((e0 & 3) ^ (r0 & 3)) * 8;
  const int r1 = e1 >> 2, c1 = ((e1 & 3) ^ (r1 & 3)) * 8;
  const bf16_t* gA0 = A + (size_t)(bm + r0) * K + c0;
  const bf16_t* gA1 = A + (size_t)(bm + r1) * K + c1;
  const bf16_t* gB0 = W + (size_t)(bn + r0) * K + c0;
  const bf16_t* gB1 = W + (size_t)(bn + r1) * K + c1;
  char* lA0 = (char*)As + wave * 1024;
  char* lA1 = (char*)As + 4096 + wave * 1024;
  char* lB0 = (char*)Bs + wave * 1024;
  char* lB1 = (char*)Bs + 4096 + wave * 1024;

  f32x4 acc[4][4] = {};

  for (int k0 = 0; k0 < K; k0 += 32) {
    __syncthreads();
    load_lds16(gA0 + k0, lA0);
    load_lds16(gA1 + k0, lA1);
    load_lds16(gB0 + k0, lB0);
    load_lds16(gB1 + k0, lB1);
    __syncthreads();
    bf16x8 af[4], bfr[4];
    for (int i = 0; i < 4; ++i) {
      int row = wm + i * 16 + col;
      af[i] = *(const bf16x8*)((const char*)As + row * 64 + ((quad ^ (row & 3)) * 16));
    }
    for (int j = 0; j < 4; ++j) {
      int row = wn + j * 16 + col;
      bfr[j] = *(const bf16x8*)((const char*)Bs + row * 64 + ((quad ^ (row & 3)) * 16));
    }
    for (int i = 0; i < 4; ++i)
      for (int j = 0; j < 4; ++j)
        acc[i][j] = __builtin_amdgcn_mfma_f32_16x16x32_bf16(af[i], bfr[j], acc[i][j], 0, 0, 0);
  }

  for (int i = 0; i < 4; ++i)
    for (int j = 0; j < 4; ++j)
      for (int r = 0; r < 4; ++r) {
        size_t row = (size_t)(bm + wm + i * 16 + quad * 4 + r);
        size_t cc  = (size_t)(bn + wn + j * 16 + col);
        C[row * N + cc] = (OutT)acc[i][j][r];
      }
}

// ---------------------------------------------------------------------------
// RoPE in place on K half of kv [MROWS,1024] (cols 0..511); Q rope is fused
// into the attention kernel.
// ---------------------------------------------------------------------------
__global__ __launch_bounds__(256) void rope_k(bf16_t* __restrict__ kv)
{
  size_t idx = (size_t)blockIdx.x * 256 + threadIdx.x;   // < MROWS*8*32
  int i = (int)(idx & 31);
  size_t hm = idx >> 5;
  int h = (int)(hm & (N_KV - 1));
  size_t m = hm >> 3;
  int t = (int)(m & (TLEN - 1));
  float inv = __builtin_exp2f(-(float)i * (13.287712379549449f / 32.0f));
  float ang = (float)t * inv;
  float sn, cs;
  sincosf(ang, &sn, &cs);
  size_t off = m * (size_t)KV_STR + (size_t)h * D_HEAD + i;
  float x1 = (float)kv[off];
  float x2 = (float)kv[off + 32];
  kv[off]      = (bf16_t)(x1 * cs - x2 * sn);
  kv[off + 32] = (bf16_t)(x2 * cs + x1 * sn);
}

// ---------------------------------------------------------------------------
// V slice+transpose: kv_buf v-part -> Vt [B*KV][64][S_PADN]
// ---------------------------------------------------------------------------
__global__ __launch_bounds__(256) void transpose_v(const bf16_t* __restrict__ KV,
                                                   bf16_t* __restrict__ Vt)
{
  __shared__ __align__(16) bf16_t tile[32][72];
  const int tid = threadIdx.x;
  const int s0  = blockIdx.x * 32;
  const int bk  = blockIdx.y;
  const int b   = bk >> 3, kvh = bk & 7;
  {
    int srow = tid >> 3;
    int dcol = (tid & 7) * 8;
    int sg = s0 + srow;
    int orig = (sg < SINK) ? sg : sg + (TLEN - WINDOW - SINK);
    if (orig > TLEN - 1) orig = TLEN - 1;   // pad rows: masked later
    const bf16_t* src = KV + (size_t)(b * TLEN + orig) * KV_STR + KV_DIM + kvh * D_HEAD + dcol;
    *(bf16x8*)&tile[srow][dcol] = *(const bf16x8*)src;
  }
  __syncthreads();
  {
    int d  = tid >> 2;
    int sc = (tid & 3) * 8;
    bf16x8 v;
    for (int j = 0; j < 8; ++j) v[j] = tile[sc + j][d];
    *(bf16x8*)(Vt + (size_t)(bk * 64 + d) * S_PADN + s0 + sc) = v;
  }
}

// ---------------------------------------------------------------------------
// Flash attention v5:
//  - ALL global->LDS via global_load_lds (vmcnt); ALL consumption via ds_read
//    (lgkmcnt). Independent counters => staging for st+1 stays in flight the
//    whole step (r4's V-from-global forced vmcnt(0) mid-step — regression).
//  - ONE barrier/step (Ps is per-wave LDS); stage(st+1) right after barrier.
//  - row-sum l via MFMA ones-fragment; Q RoPE + 0.125*log2(e) fused into Q load.
//  - LDS 50.4KB -> 3 blocks/CU.
// ---------------------------------------------------------------------------
__global__ __launch_bounds__(256, 3) void attn_kernel(const bf16_t* __restrict__ Q,
                                                      const bf16_t* __restrict__ KV,
                                                      const bf16_t* __restrict__ Vt,
                                                      bf16_t* __restrict__ ctx)
{
  __shared__ __align__(16) bf16_t Ks[2][64 * 64];
  __shared__ __align__(16) bf16_t Vs[2][64 * 64];
  __shared__ __align__(16) bf16_t Ps[4][32 * PSP];
  const int tid = threadIdx.x, lane = tid & 63, wave = tid >> 6;
  const int quad = lane >> 4, col = lane & 15;
  const int bh = blockIdx.y, b = bh >> 5, h = bh & 31, kvh = h >> 2;
  const int bkv = b * 8 + kvh;
  const int t0b = blockIdx.x * 128;
  const int tw0 = t0b + wave * 32;

  // ---- Q B-frags with fused RoPE; pair (d, d+32) = (c=0, c=1) same jj ----
  bf16x8 qf[2][2];
  {
    float invf[8];
#pragma unroll
    for (int jj = 0; jj < 8; ++jj)
      invf[jj] = __builtin_exp2f(-(float)(quad * 8 + jj) * (13.287712379549449f / 32.0f));
#pragma unroll
    for (int g = 0; g < 2; ++g) {
      const float tpos = (float)(tw0 + g * 16 + col);
      const bf16_t* qrow = Q + (size_t)(b * TLEN + tw0 + g * 16 + col) * D_MODEL + h * D_HEAD;
      bf16x8 v0 = *(const bf16x8*)(qrow + quad * 8);
      bf16x8 v1 = *(const bf16x8*)(qrow + 32 + quad * 8);
#pragma unroll
      for (int jj = 0; jj < 8; ++jj) {
        float sn, cs;
        sincosf(tpos * invf[jj], &sn, &cs);
        float x1 = (float)v0[jj], x2 = (float)v1[jj];
        qf[g][0][jj] = (bf16_t)((x1 * cs - x2 * sn) * (0.125f * LOG2E));
        qf[g][1][jj] = (bf16_t)((x2 * cs + x1 * sn) * (0.125f * LOG2E));
      }
    }
  }

  bf16x8 ones;
#pragma unroll
  for (int j = 0; j < 8; ++j) ones[j] = (bf16_t)1.0f;

  f32x4 oAcc[2][4] = {};
  f32x4 oL[2] = {};

  const int s_end  = (t0b + 128 < SEQ_S) ? t0b + 128 : SEQ_S;
  const int nsteps = (s_end + 63) >> 6;

  auto stage = [&](int st, int buf) {
    const int sb = st * 64;
#pragma unroll
    for (int kk = 0; kk < 2; ++kk) {
      int e = kk * 256 + tid;
      int srow = e >> 3;
      int cb = (e & 7) ^ (srow & 7);
      int sg = sb + srow;
      int orig = (sg < SINK) ? sg : sg + (TLEN - WINDOW - SINK);
      if (orig > TLEN - 1) orig = TLEN - 1;
      const bf16_t* gk = KV + (size_t)(b * TLEN + orig) * KV_STR + kvh * D_HEAD + cb * 8;
      load_lds16(gk, (char*)&Ks[buf][0] + kk * 4096 + wave * 1024);
      const bf16_t* gv = Vt + (size_t)(bkv * 64 + srow) * S_PADN + sb + cb * 8;
      load_lds16(gv, (char*)&Vs[buf][0] + kk * 4096 + wave * 1024);
    }
  };

  stage(0, 0);
  for (int st = 0; st < nsteps; ++st) {
    const int cur = st & 1;
    const int s0 = st * 64;
    const bool dead = (s0 > tw0 + 31);
    const bool full = (s0 + 63 <= tw0) && (s0 + 63 < SEQ_S);
    __syncthreads();                       // tiles[cur] landed; st-1 reads done
    if (st + 1 < nsteps) stage(st + 1, cur ^ 1);   // in flight all step (vmcnt)

    if (dead) continue;

    // ---- S^T = K·Q^T, per-mt to keep sacc live range small ----
#pragma unroll
    for (int mt = 0; mt < 4; ++mt) {
      const int rr = mt * 16 + col;
      f32x4 sa0 = {0.f, 0.f, 0.f, 0.f}, sa1 = {0.f, 0.f, 0.f, 0.f};
#pragma unroll
      for (int c = 0; c < 2; ++c) {
        const bf16x8 kf = *(const bf16x8*)((const char*)&Ks[cur][0] + rr * 128 +
                                           ((((c << 2) | quad) ^ (col & 7)) * 16));
        sa0 = __builtin_amdgcn_mfma_f32_16x16x32_bf16(kf, qf[0][c], sa0, 0, 0, 0);
        sa1 = __builtin_amdgcn_mfma_f32_16x16x32_bf16(kf, qf[1][c], sa1, 0, 0, 0);
      }
#pragma unroll
      for (int g = 0; g < 2; ++g) {
        const f32x4 sv = g ? sa1 : sa0;
        const int t = tw0 + g * 16 + col;
        bf16x4 pk;
#pragma unroll
        for (int r = 0; r < 4; ++r) {
          float p = __builtin_exp2f(sv[r]);
          if (!full) {
            int s = s0 + mt * 16 + quad * 4 + r;
            p = (s <= t && s < SEQ_S) ? p : 0.0f;
          }
          pk[r] = (bf16_t)p;
        }
        *(bf16x4*)(&Ps[wave][(g * 16 + col) * PSP + mt * 16 + quad * 4]) = pk;
      }
    }

    // same-wave LDS write->read: drain lgkm (cheap; ds ops in-order anyway)
    __builtin_amdgcn_s_waitcnt(0xC07F);

#pragma unroll
    for (int c = 0; c < 2; ++c) {
      bf16x8 pf0 = *(const bf16x8*)(&Ps[wave][(col) * PSP + c * 32 + quad * 8]);
      bf16x8 pf1 = *(const bf16x8*)(&Ps[wave][(16 + col) * PSP + c * 32 + quad * 8]);
      oL[0] = __builtin_amdgcn_mfma_f32_16x16x32_bf16(pf0, ones, oL[0], 0, 0, 0);
      oL[1] = __builtin_amdgcn_mfma_f32_16x16x32_bf16(pf1, ones, oL[1], 0, 0, 0);
#pragma unroll
      for (int nj = 0; nj < 4; ++nj) {
        const int vr = nj * 16 + col;
        const bf16x8 vf = *(const bf16x8*)((const char*)&Vs[cur][0] + vr * 128 +
                                           ((((c << 2) | quad) ^ (vr & 7)) * 16));
        oAcc[0][nj] = __builtin_amdgcn_mfma_f32_16x16x32_bf16(pf0, vf, oAcc[0][nj], 0, 0, 0);
        oAcc[1][nj] = __builtin_amdgcn_mfma_f32_16x16x32_bf16(pf1, vf, oAcc[1][nj], 0, 0, 0);
      }
    }
  }

#pragma unroll
  for (int g = 0; g < 2; ++g) {
    float rli[4];
#pragma unroll
    for (int r = 0; r < 4; ++r)
      rli[r] = __builtin_amdgcn_rcpf(oL[g][r]);
#pragma unroll
    for (int nj = 0; nj < 4; ++nj)
#pragma unroll
      for (int r = 0; r < 4; ++r) {
        size_t row = (size_t)(b * TLEN + tw0 + g * 16 + quad * 4 + r);
        ctx[row * D_MODEL + h * D_HEAD + nj * 16 + col] = (bf16_t)(oAcc[g][nj][r] * rli[r]);
      }
  }
}

// ---------------------------------------------------------------------------
extern "C" void kernel_launch(void* const* d_in, const int* in_sizes, int n_in,
                              void* d_out, int out_size, void* d_ws, size_t ws_size,
                              hipStream_t stream)
{
  const float* x  = (const float*)d_in[0];
  const float* wq = (const float*)d_in[1];
  const float* wk = (const float*)d_in[2];
  const float* wv = (const float*)d_in[3];
  const float* wp = (const float*)d_in[4];

  bf16_t* xb    = (bf16_t*)d_ws;
  bf16_t* wqb   = xb  + (size_t)NX;
  bf16_t* wkb   = wqb + (size_t)NWQ;     // wk rows 0..511
  bf16_t* wvb   = wkb + (size_t)NWK;     // wv rows 512..1023 (contiguous)
  bf16_t* wpb   = wvb + (size_t)NWK;
  bf16_t* q_buf = wpb + (size_t)NWQ;
  bf16_t* kv_buf = q_buf + (size_t)NX;                 // [8192,1024] k|v
  bf16_t* vt_buf = kv_buf + (size_t)MROWS * KV_STR;    // [16,64,S_PADN]
  bf16_t* c_buf  = xb;                                 // reuse x
  float*  out    = (float*)d_out;

  cvt_all<<<NALL / 1024, 256, 0, stream>>>(x, wq, wk, wv, wp, xb);

  gemm_bt<bf16_t><<<dim3(MROWS / 128, D_MODEL / 128), 256, 0, stream>>>(xb, wqb, q_buf, MROWS, D_MODEL, D_MODEL);
  gemm_bt<bf16_t><<<dim3(MROWS / 128, KV_STR / 128), 256, 0, stream>>>(xb, wkb, kv_buf, MROWS, KV_STR, D_MODEL);

  rope_k<<<(MROWS * N_KV * 32) / 256, 256, 0, stream>>>(kv_buf);
  transpose_v<<<dim3(S_PADN / 32, BATCH * N_KV), 256, 0, stream>>>(kv_buf, vt_buf);
  attn_kernel<<<dim3(TLEN / 128, BATCH * N_HEADS), 256, 0, stream>>>(q_buf, kv_buf, vt_buf, c_buf);
  gemm_bt<float><<<dim3(MROWS / 128, D_MODEL / 128), 256, 0, stream>>>(c_buf, wpb, out, MROWS, D_MODEL, D_MODEL);
}